// Round 5
// baseline (116.385 us; speedup 1.0000x reference)
//
#include <hip/hip_runtime.h>

namespace {
constexpr int Bn = 8, Cn = 256, Hn = 96, Wn = 128;
constexpr int HWn = Hn * Wn;            // 12288
constexpr int CHWn = Cn * HWn;
constexpr int ND = 9;                   // 2*MD+1
constexpr int TILESH = Hn / 2;          // 48 tiles of 2 h-rows
constexpr int NBLK = Bn * TILESH * ND;  // 3456 single-wave blocks
constexpr int PERX = NBLK / 8;          // 432 blocks/XCD -> one batch image per XCD
constexpr int CHALF = Cn / 2;           // 128 channel-steps per lane-half
}

// DPP lane shifts within 16-lane rows; bound_ctrl=true -> shifted-in lanes read 0
// (this IS the w-direction zero padding at tile edges).
__device__ __forceinline__ float dpp_shr1(float x) {  // lane i <- lane i-1 (row-local)
  return __int_as_float(__builtin_amdgcn_update_dpp(
      0, __float_as_int(x), 0x111 /*row_shr:1*/, 0xF, 0xF, true));
}
__device__ __forceinline__ float dpp_shl1(float x) {  // lane i <- lane i+1 (row-local)
  return __int_as_float(__builtin_amdgcn_update_dpp(
      0, __float_as_int(x), 0x101 /*row_shl:1*/, 0xF, 0xF, true));
}

struct Ch {
  float4 sa, sb, fa, fb;
};

__global__ __launch_bounds__(64) void corr_kernel(
    const float* __restrict__ first, const float* __restrict__ second,
    float* __restrict__ out)
{
  const int lane = threadIdx.x;
  const int bid = blockIdx.x;
  // XCD-aware swizzle: XCD x handles batch image b=x -> second re-reads stay in its L2.
  const int logical = (bid & 7) * PERX + (bid >> 3);
  const int dy = logical % ND;
  const int t = logical / ND;
  const int b = t / TILESH;
  const int h0 = (t % TILESH) * 2;

  // lane layout: 4 groups of 16 lanes. group g = lane>>4:
  //   g0: row h0,   channels 0..127     g1: row h0+1, channels 0..127
  //   g2: row h0,   channels 128..255   g3: row h0+1, channels 128..255
  const int hs = (lane >> 4) & 1;    // row within pair (16-lane DPP group = one image row)
  const int chalf = lane >> 5;       // channel half
  const int w0 = (lane & 15) << 3;   // 8 pixels per lane

  const int gr = h0 + hs + dy - 4;                    // second source row
  const float m = (gr >= 0 && gr < Hn) ? 1.0f : 0.0f; // row OOB mask (uniform per 16-group)
  const int cg = min(max(gr, 0), Hn - 1);             // clamped (safe) row

  const float* ssrc = second + b * CHWn + chalf * CHALF * HWn + cg * Wn + w0;
  const float* fsrc = first + b * CHWn + chalf * CHALF * HWn + (h0 + hs) * Wn + w0;

  float acc[ND][8];
#pragma unroll
  for (int dx = 0; dx < ND; ++dx)
#pragma unroll
    for (int p = 0; p < 8; ++p) acc[dx][p] = 0.f;

  auto LOADCH = [&](int coff) -> Ch {
    Ch r;
    r.sa = *(const float4*)(ssrc + coff);
    r.sb = *(const float4*)(ssrc + coff + 4);
    r.fa = *(const float4*)(fsrc + coff);
    r.fb = *(const float4*)(fsrc + coff + 4);
    return r;
  };

  // Row-OOB mask hoisted to epilogue (acc scales linearly by m; DPP is row-local).
  auto COMP = [&](const Ch& ch) {
    const float s[16] = {
        dpp_shr1(ch.sb.x), dpp_shr1(ch.sb.y), dpp_shr1(ch.sb.z), dpp_shr1(ch.sb.w),
        ch.sa.x, ch.sa.y, ch.sa.z, ch.sa.w,
        ch.sb.x, ch.sb.y, ch.sb.z, ch.sb.w,
        dpp_shl1(ch.sa.x), dpp_shl1(ch.sa.y), dpp_shl1(ch.sa.z), dpp_shl1(ch.sa.w)};
    const float f[8] = {ch.fa.x, ch.fa.y, ch.fa.z, ch.fa.w,
                        ch.fb.x, ch.fb.y, ch.fb.z, ch.fb.w};
#pragma unroll
    for (int dx = 0; dx < ND; ++dx)
#pragma unroll
      for (int p = 0; p < 8; ++p)
        acc[dx][p] = fmaf(f[p], s[p + dx], acc[dx][p]);
  };

  // depth-2 register pipeline over this half's 128 channel-steps (R2's proven form)
  Ch L0 = LOADCH(0);
  Ch L1 = LOADCH(HWn);
  int coff = 2 * HWn;
#pragma unroll 1
  for (int it = 0; it < (CHALF - 2) / 2; ++it) {  // 63 iters
    Ch N0 = LOADCH(coff);
    Ch N1 = LOADCH(coff + HWn);
    COMP(L0);
    COMP(L1);
    L0 = N0;
    L1 = N1;
    coff += 2 * HWn;
  }
  COMP(L0);
  COMP(L1);

  // ---- register-only cross-half combine: lane l (+) lane l^32 (same pixel,
  // other channel half). After this every lane holds the full-C sum.
#pragma unroll
  for (int dx = 0; dx < ND; ++dx)
#pragma unroll
    for (int p = 0; p < 8; ++p)
      acc[dx][p] += __shfl_xor(acc[dx][p], 32);

  const float scale = m * (1.0f / Cn);
  float* obase = out + ((b * 81 + dy * ND) * Hn + (h0 + hs)) * Wn + w0;

  // split stores: lanes 0-31 write dx 0..4, lanes 32-63 write dx 5..8
  if (lane < 32) {
#pragma unroll
    for (int dx = 0; dx < 5; ++dx) {
      float4 o0 = make_float4(acc[dx][0] * scale, acc[dx][1] * scale,
                              acc[dx][2] * scale, acc[dx][3] * scale);
      float4 o1 = make_float4(acc[dx][4] * scale, acc[dx][5] * scale,
                              acc[dx][6] * scale, acc[dx][7] * scale);
      *(float4*)(obase + dx * HWn) = o0;
      *(float4*)(obase + dx * HWn + 4) = o1;
    }
  } else {
#pragma unroll
    for (int dx = 5; dx < ND; ++dx) {
      float4 o0 = make_float4(acc[dx][0] * scale, acc[dx][1] * scale,
                              acc[dx][2] * scale, acc[dx][3] * scale);
      float4 o1 = make_float4(acc[dx][4] * scale, acc[dx][5] * scale,
                              acc[dx][6] * scale, acc[dx][7] * scale);
      *(float4*)(obase + dx * HWn) = o0;
      *(float4*)(obase + dx * HWn + 4) = o1;
    }
  }
}

extern "C" void kernel_launch(void* const* d_in, const int* in_sizes, int n_in,
                              void* d_out, int out_size, void* d_ws, size_t ws_size,
                              hipStream_t stream) {
  const float* first = (const float*)d_in[0];
  const float* second = (const float*)d_in[1];
  float* out = (float*)d_out;
  corr_kernel<<<dim3(NBLK), dim3(64), 0, stream>>>(first, second, out);
}